// Round 2
// baseline (922.531 us; speedup 1.0000x reference)
//
#include <hip/hip_runtime.h>

// Problem constants (from reference: S,P,M=(128,2048,64), NC,NB=(16,8), H,W=512, EXTENT=12, EPS=1e-9)
#define NS   128
#define NP   2048
#define NM   64
#define NCYL 16
#define NBOX 8
#define IH   512
#define IW   512
#define FEXT 12.0f
#define FEPS 1e-9f

__global__ __launch_bounds__(256) void render_kernel(
    const float* __restrict__ sources, const float* __restrict__ mpts,
    const float* __restrict__ mnrm,    const float* __restrict__ mpos,
    const float* __restrict__ mrot,
    const float* __restrict__ cp1g, const float* __restrict__ cp2g,
    const float* __restrict__ crad, const float* __restrict__ bp1g,
    const float* __restrict__ bp2g, const float* __restrict__ spp,
    const float* __restrict__ spn,  float* __restrict__ img)
{
    // Per-block LDS copies of occluder constants (precomputed once per block).
    __shared__ float s_cp1[NCYL][3], s_ca[NCYL][3], s_cL[NCYL], s_cr2[NCYL];
    __shared__ float s_b1[NBOX][3], s_b2[NBOX][3];

    const int t = threadIdx.x;
    if (t < NCYL) {
        float p1x = cp1g[t*3+0], p1y = cp1g[t*3+1], p1z = cp1g[t*3+2];
        float axx = cp2g[t*3+0] - p1x;
        float axy = cp2g[t*3+1] - p1y;
        float axz = cp2g[t*3+2] - p1z;
        float L   = sqrtf(axx*axx + axy*axy + axz*axz);
        float inv = 1.0f / (L + FEPS);
        s_cp1[t][0] = p1x; s_cp1[t][1] = p1y; s_cp1[t][2] = p1z;
        s_ca[t][0] = axx*inv; s_ca[t][1] = axy*inv; s_ca[t][2] = axz*inv;
        s_cL[t] = L;
        float r = crad[t];
        s_cr2[t] = r*r;
    } else if (t < NCYL + NBOX) {
        int b = t - NCYL;
        #pragma unroll
        for (int k = 0; k < 3; k++) {
            s_b1[b][k] = bp1g[b*3+k];
            s_b2[b][k] = bp2g[b*3+k];
        }
    }
    __syncthreads();

    const int n = blockIdx.x * 256 + t;   // point index
    const int s = blockIdx.y;             // source index
    const int m = blockIdx.z;             // mirror index

    // Block-uniform data (compiler scalarizes these into s_loads).
    float R0 = mrot[m*9+0], R1 = mrot[m*9+1], R2 = mrot[m*9+2];
    float R3 = mrot[m*9+3], R4 = mrot[m*9+4], R5 = mrot[m*9+5];
    float R6 = mrot[m*9+6], R7 = mrot[m*9+7], R8 = mrot[m*9+8];
    float posx = mpos[m*3+0], posy = mpos[m*3+1], posz = mpos[m*3+2];
    float sx = sources[s*3+0], sy = sources[s*3+1], sz = sources[s*3+2];
    float sppx = spp[0], sppy = spp[1], sppz = spp[2];
    float spnx = spn[0], spny = spn[1], spnz = spn[2];

    const long idx = ((long)m * NP + n) * 3;
    float px = mpts[idx+0], py = mpts[idx+1], pz = mpts[idx+2];
    float nx = mnrm[idx+0], ny = mnrm[idx+1], nz = mnrm[idx+2];

    // tp = R @ p + pos ; tn = R @ n   (einsum 'mij,mnj->mni')
    float tpx = R0*px + R1*py + R2*pz + posx;
    float tpy = R3*px + R4*py + R5*pz + posy;
    float tpz = R6*px + R7*py + R8*pz + posz;
    float tnx = R0*nx + R1*ny + R2*nz;
    float tny = R3*nx + R4*ny + R5*nz;
    float tnz = R6*nx + R7*ny + R8*nz;

    // d = normalize(tp - source)
    float dx = tpx - sx, dy = tpy - sy, dz = tpz - sz;
    float invl = 1.0f / sqrtf(dx*dx + dy*dy + dz*dz);
    dx *= invl; dy *= invl; dz *= invl;
    // u = -d (shadow ray toward source)
    float ux = -dx, uy = -dy, uz = -dz;

    bool hit = false;

    #pragma unroll
    for (int c = 0; c < NCYL; c++) {
        float ocx = tpx - s_cp1[c][0], ocy = tpy - s_cp1[c][1], ocz = tpz - s_cp1[c][2];
        float ax = s_ca[c][0], ay = s_ca[c][1], az = s_ca[c][2];
        float ua = ux*ax + uy*ay + uz*az;
        float oa = ocx*ax + ocy*ay + ocz*az;
        float ddx = ux - ua*ax, ddy = uy - ua*ay, ddz = uz - ua*az;
        float mx = ocx - oa*ax, my = ocy - oa*ay, mz = ocz - oa*az;
        float A = ddx*ddx + ddy*ddy + ddz*ddz;
        float B = 2.0f * (mx*ddx + my*ddy + mz*ddz);
        float Cc = mx*mx + my*my + mz*mz - s_cr2[c];
        float disc = B*B - 4.0f*A*Cc;
        if (disc > 0.0f) {
            float sq  = sqrtf(disc);
            float i2a = 1.0f / (2.0f*A + FEPS);
            float t1 = (-B - sq) * i2a;
            float t2 = (-B + sq) * i2a;
            float ax1 = oa + t1*ua;
            float ax2 = oa + t2*ua;
            float L = s_cL[c];
            hit = hit || (t1 > FEPS && ax1 >= 0.0f && ax1 <= L)
                      || (t2 > FEPS && ax2 >= 0.0f && ax2 <= L);
        }
    }

    if (!hit) {
        float ivx = 1.0f / ((fabsf(ux) < FEPS) ? FEPS : ux);
        float ivy = 1.0f / ((fabsf(uy) < FEPS) ? FEPS : uy);
        float ivz = 1.0f / ((fabsf(uz) < FEPS) ? FEPS : uz);
        #pragma unroll
        for (int b = 0; b < NBOX; b++) {
            float t0x = (s_b1[b][0] - tpx) * ivx, t1x = (s_b2[b][0] - tpx) * ivx;
            float t0y = (s_b1[b][1] - tpy) * ivy, t1y = (s_b2[b][1] - tpy) * ivy;
            float t0z = (s_b1[b][2] - tpz) * ivz, t1z = (s_b2[b][2] - tpz) * ivz;
            float tmin = fmaxf(fmaxf(fminf(t0x,t1x), fminf(t0y,t1y)), fminf(t0z,t1z));
            float tmax = fminf(fminf(fmaxf(t0x,t1x), fmaxf(t0y,t1y)), fmaxf(t0z,t1z));
            hit = hit || (tmax >= fmaxf(tmin, FEPS));
        }
    }

    if (!hit) {
        float dn = dx*tnx + dy*tny + dz*tnz;
        float rx = dx - 2.0f*dn*tnx;
        float ry = dy - 2.0f*dn*tny;
        float rz = dz - 2.0f*dn*tnz;
        float cosv = fabsf(dn);
        float denom = rx*spnx + ry*spny + rz*spnz;
        float tt = ((sppx-tpx)*spnx + (sppy-tpy)*spny + (sppz-tpz)*spnz) / (denom + FEPS);
        float qx = tpx + tt*rx;
        float qy = tpy + tt*ry;
        float fx = (qx + FEXT) / (2.0f*FEXT) * (float)IW;
        float fy = (qy + FEXT) / (2.0f*FEXT) * (float)IH;
        float fxf = floorf(fx), fyf = floorf(fy);
        if (fxf >= 0.0f && fxf < (float)IW && fyf >= 0.0f && fyf < (float)IH) {
            int ix = (int)fxf, iy = (int)fyf;
            atomicAdd(&img[iy*IW + ix], cosv);
        }
    }
}

extern "C" void kernel_launch(void* const* d_in, const int* in_sizes, int n_in,
                              void* d_out, int out_size, void* d_ws, size_t ws_size,
                              hipStream_t stream) {
    const float* sources = (const float*)d_in[0];
    const float* mpts    = (const float*)d_in[1];
    const float* mnrm    = (const float*)d_in[2];
    const float* mpos    = (const float*)d_in[3];
    const float* mrot    = (const float*)d_in[4];
    const float* cp1     = (const float*)d_in[5];
    const float* cp2     = (const float*)d_in[6];
    const float* crad    = (const float*)d_in[7];
    const float* bp1     = (const float*)d_in[8];
    const float* bp2     = (const float*)d_in[9];
    const float* spp     = (const float*)d_in[10];
    const float* spn     = (const float*)d_in[11];
    // d_in[12], d_in[13] = sensor_h, sensor_w (int, fixed at 512 — baked in)

    float* img = (float*)d_out;  // fp32 accumulator IS the output (harness poisons it -> zero it)
    hipMemsetAsync(img, 0, (size_t)IH * IW * sizeof(float), stream);

    dim3 grid(NP / 256, NS, NM);  // (8, 128, 64) blocks of 256 = one thread per ray
    render_kernel<<<grid, 256, 0, stream>>>(sources, mpts, mnrm, mpos, mrot,
                                            cp1, cp2, crad, bp1, bp2, spp, spn, img);
}

// Round 3
// 899.675 us; speedup vs baseline: 1.0254x; 1.0254x over previous
//
#include <hip/hip_runtime.h>

// Problem constants (from reference: S,P,M=(128,2048,64), NC,NB=(16,8), H,W=512, EXTENT=12, EPS=1e-9)
#define NS   128
#define NP   2048
#define NM   64
#define NCYL 16
#define NBOX 8
#define IH   512
#define IW   512
#define FEXT 12.0f
#define FEPS 1e-9f
#define PXSCALE ((float)IW / (2.0f * FEXT))   // 21.3333...

__device__ __forceinline__ float frcp(float x)  { return __builtin_amdgcn_rcpf(x); }
__device__ __forceinline__ float frsq(float x)  { return __builtin_amdgcn_rsqf(x); }
__device__ __forceinline__ float fsqrt(float x) { return __builtin_amdgcn_sqrtf(x); }

__global__ __launch_bounds__(256) void render_kernel(
    const float* __restrict__ sources, const float* __restrict__ mpts,
    const float* __restrict__ mnrm,    const float* __restrict__ mpos,
    const float* __restrict__ mrot,
    const float* __restrict__ cp1g, const float* __restrict__ cp2g,
    const float* __restrict__ crad, const float* __restrict__ bp1g,
    const float* __restrict__ bp2g, const float* __restrict__ spp,
    const float* __restrict__ spn,  float* __restrict__ img)
{
    // Packed per-block LDS occluder constants -> ds_read_b128.
    // cyl[c][0] = (p1x,p1y,p1z, L) ; cyl[c][1] = (ax,ay,az, r^2)
    // box[b][0] = (b1x,b1y,b1z, 0) ; box[b][1] = (b2x,b2y,b2z, 0)
    __shared__ float4 s_cyl[NCYL][2];
    __shared__ float4 s_box[NBOX][2];

    const int t = threadIdx.x;
    if (t < NCYL) {
        float p1x = cp1g[t*3+0], p1y = cp1g[t*3+1], p1z = cp1g[t*3+2];
        float axx = cp2g[t*3+0] - p1x;
        float axy = cp2g[t*3+1] - p1y;
        float axz = cp2g[t*3+2] - p1z;
        float L   = sqrtf(axx*axx + axy*axy + axz*axz);
        float inv = 1.0f / (L + FEPS);
        float r   = crad[t];
        s_cyl[t][0] = make_float4(p1x, p1y, p1z, L);
        s_cyl[t][1] = make_float4(axx*inv, axy*inv, axz*inv, r*r);
    } else if (t < NCYL + NBOX) {
        int b = t - NCYL;
        s_box[b][0] = make_float4(bp1g[b*3+0], bp1g[b*3+1], bp1g[b*3+2], 0.0f);
        s_box[b][1] = make_float4(bp2g[b*3+0], bp2g[b*3+1], bp2g[b*3+2], 0.0f);
    }
    __syncthreads();

    const int n = blockIdx.x * 256 + t;   // point index
    const int s = blockIdx.y;             // source index
    const int m = blockIdx.z;             // mirror index

    // Block-uniform data (compiler scalarizes into s_loads).
    float R0 = mrot[m*9+0], R1 = mrot[m*9+1], R2 = mrot[m*9+2];
    float R3 = mrot[m*9+3], R4 = mrot[m*9+4], R5 = mrot[m*9+5];
    float R6 = mrot[m*9+6], R7 = mrot[m*9+7], R8 = mrot[m*9+8];
    float posx = mpos[m*3+0], posy = mpos[m*3+1], posz = mpos[m*3+2];
    float sx = sources[s*3+0], sy = sources[s*3+1], sz = sources[s*3+2];
    float sppx = spp[0], sppy = spp[1], sppz = spp[2];
    float spnx = spn[0], spny = spn[1], spnz = spn[2];

    const long idx = ((long)m * NP + n) * 3;
    float px = mpts[idx+0], py = mpts[idx+1], pz = mpts[idx+2];
    float nx = mnrm[idx+0], ny = mnrm[idx+1], nz = mnrm[idx+2];

    // tp = R @ p + pos ; tn = R @ n
    float tpx = R0*px + R1*py + R2*pz + posx;
    float tpy = R3*px + R4*py + R5*pz + posy;
    float tpz = R6*px + R7*py + R8*pz + posz;
    float tnx = R0*nx + R1*ny + R2*nz;
    float tny = R3*nx + R4*ny + R5*nz;
    float tnz = R6*nx + R7*ny + R8*nz;

    // d = normalize(tp - source)
    float dx = tpx - sx, dy = tpy - sy, dz = tpz - sz;
    float invl = frsq(dx*dx + dy*dy + dz*dz);
    dx *= invl; dy *= invl; dz *= invl;
    // u = -d (shadow ray toward source)
    float ux = -dx, uy = -dy, uz = -dz;

    bool hit = false;

    #pragma unroll
    for (int c = 0; c < NCYL; c++) {
        float4 c0 = s_cyl[c][0];   // p1, L
        float4 c1 = s_cyl[c][1];   // a, r^2
        float ocx = tpx - c0.x, ocy = tpy - c0.y, ocz = tpz - c0.z;
        float ua = ux*c1.x + uy*c1.y + uz*c1.z;
        float oa = ocx*c1.x + ocy*c1.y + ocz*c1.z;
        float ddx = ux - ua*c1.x, ddy = uy - ua*c1.y, ddz = uz - ua*c1.z;
        float mx = ocx - oa*c1.x, my = ocy - oa*c1.y, mz = ocz - oa*c1.z;
        float A = ddx*ddx + ddy*ddy + ddz*ddz;
        float B = 2.0f * (mx*ddx + my*ddy + mz*ddz);
        float Cc = mx*mx + my*my + mz*mz - c1.w;
        float disc = B*B - 4.0f*A*Cc;
        if (disc > 0.0f) {
            float sq  = fsqrt(disc);
            float i2a = frcp(2.0f*A + FEPS);
            float t1 = (-B - sq) * i2a;
            float t2 = (-B + sq) * i2a;
            float ax1 = oa + t1*ua;
            float ax2 = oa + t2*ua;
            float L = c0.w;
            hit = hit || (t1 > FEPS && ax1 >= 0.0f && ax1 <= L)
                      || (t2 > FEPS && ax2 >= 0.0f && ax2 <= L);
        }
    }

    if (!hit) {
        float ivx = frcp((fabsf(ux) < FEPS) ? FEPS : ux);
        float ivy = frcp((fabsf(uy) < FEPS) ? FEPS : uy);
        float ivz = frcp((fabsf(uz) < FEPS) ? FEPS : uz);
        #pragma unroll
        for (int b = 0; b < NBOX; b++) {
            float4 b1 = s_box[b][0];
            float4 b2 = s_box[b][1];
            float t0x = (b1.x - tpx) * ivx, t1x = (b2.x - tpx) * ivx;
            float t0y = (b1.y - tpy) * ivy, t1y = (b2.y - tpy) * ivy;
            float t0z = (b1.z - tpz) * ivz, t1z = (b2.z - tpz) * ivz;
            float tmin = fmaxf(fmaxf(fminf(t0x,t1x), fminf(t0y,t1y)), fminf(t0z,t1z));
            float tmax = fminf(fminf(fmaxf(t0x,t1x), fmaxf(t0y,t1y)), fmaxf(t0z,t1z));
            hit = hit || (tmax >= fmaxf(tmin, FEPS));
        }
    }

    if (!hit) {
        float dn = dx*tnx + dy*tny + dz*tnz;
        float rx = dx - 2.0f*dn*tnx;
        float ry = dy - 2.0f*dn*tny;
        float rz = dz - 2.0f*dn*tnz;
        float cosv = fabsf(dn);
        float denom = rx*spnx + ry*spny + rz*spnz;
        float num   = (sppx-tpx)*spnx + (sppy-tpy)*spny + (sppz-tpz)*spnz;
        float tt = num * frcp(denom + FEPS);
        float qx = tpx + tt*rx;
        float qy = tpy + tt*ry;
        float fx = (qx + FEXT) * PXSCALE;
        float fy = (qy + FEXT) * PXSCALE;
        float fxf = floorf(fx), fyf = floorf(fy);
        if (fxf >= 0.0f && fxf < (float)IW && fyf >= 0.0f && fyf < (float)IH) {
            int ix = (int)fxf, iy = (int)fyf;
            atomicAdd(&img[iy*IW + ix], cosv);
        }
    }
}

extern "C" void kernel_launch(void* const* d_in, const int* in_sizes, int n_in,
                              void* d_out, int out_size, void* d_ws, size_t ws_size,
                              hipStream_t stream) {
    const float* sources = (const float*)d_in[0];
    const float* mpts    = (const float*)d_in[1];
    const float* mnrm    = (const float*)d_in[2];
    const float* mpos    = (const float*)d_in[3];
    const float* mrot    = (const float*)d_in[4];
    const float* cp1     = (const float*)d_in[5];
    const float* cp2     = (const float*)d_in[6];
    const float* crad    = (const float*)d_in[7];
    const float* bp1     = (const float*)d_in[8];
    const float* bp2     = (const float*)d_in[9];
    const float* spp     = (const float*)d_in[10];
    const float* spn     = (const float*)d_in[11];

    float* img = (float*)d_out;  // fp32 accumulator IS the output (harness poisons it -> zero it)
    hipMemsetAsync(img, 0, (size_t)IH * IW * sizeof(float), stream);

    dim3 grid(NP / 256, NS, NM);  // (8, 128, 64) blocks of 256 = one thread per ray
    render_kernel<<<grid, 256, 0, stream>>>(sources, mpts, mnrm, mpos, mrot,
                                            cp1, cp2, crad, bp1, bp2, spp, spn, img);
}